// Round 13
// baseline (75.207 us; speedup 1.0000x reference)
//
#include <hip/hip_runtime.h>
#include <hip/hip_bf16.h>

#define HOP 256
#define NB 16
#define NT 1024
#define MM (NB*NT)                 // 16384
#define LOUT ((NT-1)*HOP + 1024)   // 262912
#define CQ (2.0f/(3.0f*1024.0f))   // (HOP/sum(win^2))/NFFT
#define PACK_BLOCKS 2048           // 16 b x 8 f-tiles x 16 t-tiles

typedef __bf16 bf16x8 __attribute__((ext_vector_type(8)));
typedef float f32x4 __attribute__((ext_vector_type(4)));
typedef float f32x16 __attribute__((ext_vector_type(16)));

__device__ __forceinline__ void gload_lds16(const void* g, void* l) {
  __builtin_amdgcn_global_load_lds(
      (const __attribute__((address_space(1))) void*)g,
      (__attribute__((address_space(3))) void*)l, 16, 0, 0);
}

// Fused prep.
// Blocks [0,PACK_BLOCKS): pack x -> A' bf16 (A'[m][c]: c<512 re x[b][c][t],
//   c>=512 im x[b][c-512][t]) + re512[m] = x[b][512][t][0].
// Blocks [PACK_BLOCKS,+4096): B''[j][c] = sc_f*win[j]*CQ*(c<512 ? cos(2pi f j/1024)
//   : -sin(2pi f j/1024)), f=c&511 — DIRECT rows: C[m][j] = frame[j] for all j.
//   s_tab[j] = (-1)^j*win[j]*CQ (f=512 rank-1 column factor).
__global__ void prep(const float* __restrict__ x, __hip_bfloat16* __restrict__ A,
                     float* __restrict__ re512,
                     __hip_bfloat16* __restrict__ Bp, float* __restrict__ s_tab) {
  int tid = threadIdx.x;
  if (blockIdx.x >= PACK_BLOCKS) {
    int idx = (blockIdx.x - PACK_BLOCKS) * 256 + tid;   // [0, 1024*1024)
    int j = idx >> 10, c = idx & 1023;
    int f = c & 511;
    const float w0 = 6.283185307179586f / 1024.f;
    int ph = (f * j) & 1023;
    float si, co;
    __sincosf((float)ph * w0, &si, &co);
    float wn = 0.5f - 0.5f * __cosf((float)j * w0);
    float sc = (f == 0) ? 1.f : 2.f;
    float bb = sc * CQ * wn;
    float v = (c < 512) ? co * bb : -si * bb;
    Bp[idx] = __float2bfloat16(v);
    if (idx < 1024) {
      float wn2 = 0.5f - 0.5f * __cosf((float)idx * w0);
      s_tab[idx] = ((idx & 1) ? -1.f : 1.f) * wn2 * CQ;
    }
    return;
  }
  __shared__ float2 tile[64][65];
  int w = blockIdx.x;
  int b = w >> 7, fy = (w >> 4) & 7, tx = w & 15;
  int f0 = fy * 64, t0 = tx * 64;
  int tl = tid & 63, th = tid >> 6;
#pragma unroll
  for (int r = 0; r < 16; ++r) {
    int fl = r * 4 + th;
    tile[fl][tl] = *(const float2*)(x + (((size_t)b * 513 + f0 + fl) * 1024 + (t0 + tl)) * 2);
  }
  __syncthreads();
  int row = tid >> 2;
#pragma unroll
  for (int i = 0; i < 2; ++i) {
    int g = (tid & 3) * 2 + i;       // 0..7 -> 8 consecutive f's
    bf16x8 pr, pi;
#pragma unroll
    for (int e = 0; e < 8; ++e) {
      float2 v = tile[g * 8 + e][row];
      pr[e] = (__bf16)v.x;
      pi[e] = (__bf16)v.y;
    }
    size_t rowm = (size_t)(b * 1024 + t0 + row) * 1024 + f0 + g * 8;
    *(bf16x8*)(A + rowm) = pr;
    *(bf16x8*)(A + rowm + 512) = pi;
  }
  if (fy == 0 && tid < 64)
    re512[b * 1024 + t0 + tid] = x[(((size_t)b * 513 + 512) * 1024 + t0 + tid) * 2];
}

// 256x256 tile, BK=64, 8 waves (2Mx4N), 8-phase counted-vmcnt schedule (T3+T4),
// 3-bit slot swizzle (pre-swizzled source + matching fragment XOR, rule 21),
// setprio (T5), XCD swizzle (T1). MFMA = 32x32x16 (faster pipe, half the
// instructions); phase Q = one 32-row m-block so the A-granule dependency
// pattern (and thus the VMCNT schedule) is identical to the verified 16x16
// version. Epilogue adds rank-1 f=512 term; C/D layout per m74/m101:
// row=(r&3)+8*(r>>2)+4*(lane>>5), col=lane&31.
__global__ __launch_bounds__(512, 1) void gemm8(
    const __hip_bfloat16* __restrict__ A, const __hip_bfloat16* __restrict__ Bp,
    const float* __restrict__ re512, const float* __restrict__ s_tab,
    __hip_bfloat16* __restrict__ C) {
  __shared__ __align__(16) __hip_bfloat16 smem[65536];  // 128 KB
  int tid = threadIdx.x, lane = tid & 63, wv = tid >> 6;
  int wr = wv >> 2, wc = wv & 3;
  int nf = (blockIdx.x & 7) * 32 + (blockIdx.x >> 3);   // XCD swizzle, 256%8==0
  int M0 = (nf & 63) * 256, N0 = (nf >> 6) * 256;

  __hip_bfloat16* sA0 = smem;
  __hip_bfloat16* sA1 = smem + 16384;
  __hip_bfloat16* sB0 = smem + 32768;
  __hip_bfloat16* sB1 = smem + 49152;

  f32x16 acc[4][2] = {};

#define SG(X, R0, KT, G, LB)                                                   \
  {                                                                            \
    int r_ = (G) * 64 + (tid >> 3);                                            \
    int s_ = (((tid & 7) ^ (r_ & 7)) * 8);                                     \
    gload_lds16((X) + (size_t)((R0) + r_) * 1024 + (KT) * 64 + s_,             \
                (LB) + (G) * 4096 + tid * 8);                                  \
  }
#define VMCNT(N) asm volatile("s_waitcnt vmcnt(" #N ")" ::: "memory")
#define BAR() __builtin_amdgcn_s_barrier()

#define LOADA(CA, Q)                                                           \
  {                                                                            \
    int row = wr * 128 + (Q) * 32 + (lane & 31);                               \
    _Pragma("unroll") for (int ks = 0; ks < 4; ++ks)                           \
        af[ks] = *(const bf16x8*)&(CA)[row * 64 +                              \
            (((ks * 2 + (lane >> 5)) ^ (row & 7)) * 8)];                       \
  }
#define MFMAQ(Q)                                                               \
  __builtin_amdgcn_s_setprio(1);                                               \
  _Pragma("unroll") for (int ks = 0; ks < 4; ++ks)                             \
  _Pragma("unroll") for (int ni = 0; ni < 2; ++ni)                             \
      acc[Q][ni] = __builtin_amdgcn_mfma_f32_32x32x16_bf16(                    \
          af[ks], bfr[ni][ks], acc[Q][ni], 0, 0, 0);                           \
  __builtin_amdgcn_s_setprio(0);

// One K-tile: 4 phases, staging + counted-vmcnt placement identical to the
// verified 16x16 schedule (phases 0-1 read A g0/g2, phases 2-3 read g1/g3).
#define TILE(CA, CB, NA, NBUF, K1, DOST)                                       \
  {                                                                            \
    bf16x8 bfr[2][4], af[4];                                                   \
    _Pragma("unroll") for (int ni = 0; ni < 2; ++ni) {                         \
      int row = wc * 64 + ni * 32 + (lane & 31);                               \
      _Pragma("unroll") for (int ks = 0; ks < 4; ++ks)                         \
          bfr[ni][ks] = *(const bf16x8*)&(CB)[row * 64 +                       \
              (((ks * 2 + (lane >> 5)) ^ (row & 7)) * 8)];                     \
    }                                                                          \
    LOADA(CA, 0);                                                              \
    if (DOST) { SG(Bp, N0, K1, 0, NBUF); SG(Bp, N0, K1, 1, NBUF); }            \
    BAR(); MFMAQ(0); BAR();                                                    \
    LOADA(CA, 1);                                                              \
    if (DOST) { SG(Bp, N0, K1, 2, NBUF); SG(Bp, N0, K1, 3, NBUF); }            \
    BAR(); MFMAQ(1);                                                           \
    if (DOST) { VMCNT(4); } else { VMCNT(0); }                                 \
    BAR();                                                                     \
    LOADA(CA, 2);                                                              \
    if (DOST) { SG(A, M0, K1, 0, NA); SG(A, M0, K1, 2, NA); }                  \
    BAR(); MFMAQ(2); BAR();                                                    \
    LOADA(CA, 3);                                                              \
    if (DOST) { SG(A, M0, K1, 1, NA); SG(A, M0, K1, 3, NA); }                  \
    BAR(); MFMAQ(3);                                                           \
    if (DOST) { VMCNT(2); }                                                    \
    BAR();                                                                     \
  }

  // prologue: tile 0 -> buf0 (order: B g0..g3, A g0,g2 then g1,g3)
  SG(Bp, N0, 0, 0, sB0); SG(Bp, N0, 0, 1, sB0);
  SG(Bp, N0, 0, 2, sB0); SG(Bp, N0, 0, 3, sB0);
  SG(A, M0, 0, 0, sA0);  SG(A, M0, 0, 2, sA0);
  SG(A, M0, 0, 1, sA0);  SG(A, M0, 0, 3, sA0);
  VMCNT(2);   // B g0..3 + A g0,g2 landed; A g1,g3 still in flight
  BAR();

  for (int tt = 0; tt < 7; ++tt) {
    TILE(sA0, sB0, sA1, sB1, 2 * tt + 1, 1);
    TILE(sA1, sB1, sA0, sB0, 2 * tt + 2, 1);
  }
  TILE(sA0, sB0, sA1, sB1, 15, 1);   // tile 14 (stages tile 15)
  TILE(sA1, sB1, sA0, sB0, 0, 0);    // tile 15 (no stage; mid VMCNT(0))

  // epilogue: add rank-1 term, bounce through LDS, coalesced bf16 stores
  __hip_bfloat16* ct = smem;
  float snv[2];
#pragma unroll
  for (int ni = 0; ni < 2; ++ni)
    snv[ni] = s_tab[N0 + wc * 64 + ni * 32 + (lane & 31)];
#pragma unroll
  for (int mi = 0; mi < 4; ++mi) {
#pragma unroll
    for (int g = 0; g < 4; ++g) {
      int rbase = wr * 128 + mi * 32 + g * 8 + 4 * (lane >> 5);
      float4 rv = *(const float4*)&re512[M0 + rbase];
#pragma unroll
      for (int ni = 0; ni < 2; ++ni) {
        int col = wc * 64 + ni * 32 + (lane & 31);
#pragma unroll
        for (int e = 0; e < 4; ++e) {
          float val = acc[mi][ni][g * 4 + e] + ((const float*)&rv)[e] * snv[ni];
          ct[(rbase + e) * 256 + col] = __float2bfloat16(val);
        }
      }
    }
  }
  BAR();
#pragma unroll
  for (int k = 0; k < 16; ++k) {
    int row = k * 16 + (tid >> 5);
    int c0 = (tid & 31) * 8;
    *(int4*)(C + (size_t)(M0 + row) * 1024 + N0 + c0) = *(const int4*)&ct[row * 256 + c0];
  }
#undef SG
#undef VMCNT
#undef BAR
#undef LOADA
#undef MFMAQ
#undef TILE
}

// OLA: out[b][256q+r] = sum_{t=q-3..q, clamped} C[b*1024+t][(256q+r)-256t].
// Interior q: 4 contiguous aligned bf16x8 spans. Edge q: clamped scalar path.
__global__ void ola2(const __hip_bfloat16* __restrict__ C, float* __restrict__ out) {
  int q = blockIdx.x;                        // 0..1026
  int b = blockIdx.y * 8 + (threadIdx.x >> 5);
  int r0 = (threadIdx.x & 31) * 8;
  size_t outl = (size_t)b * LOUT + q * 256 + r0;
  if (q >= 3 && q < 1024) {
    size_t mrow = ((size_t)b * 1024 + q) * 1024;
    bf16x8 v0 = *(const bf16x8*)&C[mrow + r0];
    bf16x8 v1 = *(const bf16x8*)&C[mrow - 1024 + 256 + r0];
    bf16x8 v2 = *(const bf16x8*)&C[mrow - 2048 + 512 + r0];
    bf16x8 v3 = *(const bf16x8*)&C[mrow - 3072 + 768 + r0];
    float res[8];
#pragma unroll
    for (int e = 0; e < 8; ++e)
      res[e] = (float)v0[e] + (float)v1[e] + (float)v2[e] + (float)v3[e];
    *(float4*)(out + outl) = make_float4(res[0], res[1], res[2], res[3]);
    *(float4*)(out + outl + 4) = make_float4(res[4], res[5], res[6], res[7]);
    return;
  }
#pragma unroll
  for (int e = 0; e < 8; ++e) {
    int l = q * 256 + r0 + e;
    int thi = l >> 8; if (thi > 1023) thi = 1023;
    int tlo = (l - 768) >> 8; if (tlo < 0) tlo = 0;
    float s = 0.f;
    for (int t = tlo; t <= thi; ++t)
      s += __bfloat162float(C[((size_t)b * 1024 + t) * 1024 + (l - (t << 8))]);
    out[outl + e] = s;
  }
}

extern "C" void kernel_launch(void* const* d_in, const int* in_sizes, int n_in,
                              void* d_out, int out_size, void* d_ws, size_t ws_size,
                              hipStream_t stream) {
  (void)in_sizes; (void)n_in; (void)out_size; (void)ws_size;
  const float* x = (const float*)d_in[0];
  float* out = (float*)d_out;
  char* ws = (char*)d_ws;
  size_t oA  = 0;
  size_t oB  = oA + (size_t)MM * 1024 * 2;         // 33.55 MB
  size_t oS  = oB + (size_t)1024 * 1024 * 2;       // +2 MB
  size_t oR5 = oS + 1024 * 4;
  size_t oC  = oR5 + (size_t)MM * 4;
  __hip_bfloat16* A  = (__hip_bfloat16*)(ws + oA);
  __hip_bfloat16* Bp = (__hip_bfloat16*)(ws + oB);
  float* s_tab = (float*)(ws + oS);
  float* re512 = (float*)(ws + oR5);
  __hip_bfloat16* C  = (__hip_bfloat16*)(ws + oC);

  prep<<<dim3(PACK_BLOCKS + 4096), dim3(256), 0, stream>>>(x, A, re512, Bp, s_tab);
  gemm8<<<dim3(256), dim3(512), 0, stream>>>(A, Bp, re512, s_tab, C);
  ola2<<<dim3(1027, 2), dim3(256), 0, stream>>>(C, out);
}

// Round 14
// 64.112 us; speedup vs baseline: 1.1731x; 1.1731x over previous
//
#include <hip/hip_runtime.h>
#include <hip/hip_bf16.h>

#define HOP 256
#define NB 16
#define NT 1024
#define MM (NB*NT)                 // 16384
#define LOUT ((NT-1)*HOP + 1024)   // 262912
#define CQ (2.0f/(3.0f*1024.0f))   // (HOP/sum(win^2))/NFFT
#define PACK_BLOCKS 2048           // 16 b x 8 f-tiles x 16 t-tiles

typedef __bf16 bf16x8 __attribute__((ext_vector_type(8)));
typedef float f32x4 __attribute__((ext_vector_type(4)));

__device__ __forceinline__ void gload_lds16(const void* g, void* l) {
  __builtin_amdgcn_global_load_lds(
      (const __attribute__((address_space(1))) void*)g,
      (__attribute__((address_space(3))) void*)l, 16, 0, 0);
}

// Radix-2 frequency split.
// A2[m][c]: c in [0,257): re f=2c | [257,512): im f=2(c-256) | [512,768): re f=2(c-512)+1
//   | [768,1024): im f=2(c-768)+1.  (im f=0 dropped: zero kernel; re f=512 at c=256.)
// B3[row][c], row in [0,1024): nt=row>>8, i=row&255; i<128: E-row j=nt*128+i,
//   i>=128: O-row j=nt*128+i-128. Even rows: c<257: sc*cos(2pi*2c*j/1024),
//   c>=257: -2*sin(2pi*2(c-256)*j/1024). Odd rows: c<256: 2*cos(2pi*(2c+1)j/1024),
//   c>=256: -2*sin(2pi*(2(c-256)+1)j/1024).  sc = (f==0||f==512)?1:2.
// E[m][j]=sum_c A2[m][c<512]*B3e, O likewise on the odd half.
// frame[j]=wint[j]*(E+O), frame[j+512]=wint[j+512]*(E-O), wint[j]=win[j]*CQ.
__global__ void prep(const float* __restrict__ x, __hip_bfloat16* __restrict__ A,
                     __hip_bfloat16* __restrict__ B3, float* __restrict__ wint) {
  int tid = threadIdx.x;
  if (blockIdx.x >= PACK_BLOCKS) {
    int idx = (blockIdx.x - PACK_BLOCKS) * 256 + tid;   // [0, 1024*512)
    int row = idx >> 9, c = idx & 511;
    int i = row & 255, nt = row >> 8;
    int oddh = i >> 7;
    int j = nt * 128 + (i & 127);
    int f, isSin;
    if (!oddh) {
      if (c < 257) { f = 2 * c; isSin = 0; } else { f = 2 * (c - 256); isSin = 1; }
    } else {
      if (c < 256) { f = 2 * c + 1; isSin = 0; } else { f = 2 * (c - 256) + 1; isSin = 1; }
    }
    const float w0 = 6.283185307179586f / 1024.f;
    int ph = (f * j) & 1023;
    float si, co;
    __sincosf((float)ph * w0, &si, &co);
    float sc = (f == 0 || f == 512) ? 1.f : 2.f;
    B3[idx] = __float2bfloat16(isSin ? -si * sc : co * sc);
    if (idx < 1024)
      wint[idx] = (0.5f - 0.5f * __cosf((float)idx * w0)) * CQ;
    return;
  }
  __shared__ float2 tile[64][65];
  int w = blockIdx.x;
  int b = w >> 7, fy = (w >> 4) & 7, tx = w & 15;
  int f0 = fy * 64, t0 = tx * 64;
  int tl = tid & 63, th = tid >> 6;
#pragma unroll
  for (int r = 0; r < 16; ++r) {
    int fl = r * 4 + th;
    tile[fl][tl] = *(const float2*)(x + (((size_t)b * 513 + f0 + fl) * 1024 + (t0 + tl)) * 2);
  }
  __syncthreads();
  int row = tid >> 2, s = tid & 3;
  float sp = 0.f;
  if (fy == 0 && s == 1)
    sp = x[(((size_t)b * 513 + 512) * 1024 + t0 + row) * 2];   // re512 -> c=256
  int cbase = (s & 1) * 256 + (s >> 1) * 512 + f0 / 2;
#pragma unroll
  for (int v = 0; v < 4; ++v) {
    bf16x8 pv;
#pragma unroll
    for (int u = 0; u < 8; ++u) {
      int e = v * 8 + u;
      float2 tv = tile[2 * e + (s >> 1)][row];
      float val = (s & 1) ? tv.y : tv.x;
      if (fy == 0 && s == 1 && e == 0) val = sp;   // replace dropped im f=0
      pv[u] = (__bf16)val;
    }
    *(bf16x8*)(A + (size_t)(b * 1024 + t0 + row) * 1024 + cbase + v * 8) = pv;
  }
}

// 256m x 128j tile (E and O accumulators), BK=64, 8 waves (2M x 4N), counted-vmcnt
// double-buffered schedule (T3+T4), 3-bit slot swizzle (rule 21), setprio (T5),
// XCD swizzle (T1). K-tiles 0..7 accumulate E (even channels / Be rows),
// 8..15 accumulate O. Epilogue: frame[j]=wint[j](E+O), frame[j+512]=wint[j+512](E-O).
__global__ __launch_bounds__(512, 1) void gemm8(
    const __hip_bfloat16* __restrict__ A, const __hip_bfloat16* __restrict__ B3,
    const float* __restrict__ wint, __hip_bfloat16* __restrict__ C) {
  __shared__ __align__(16) __hip_bfloat16 smem[65536];  // 128 KB (96 pipeline + ct)
  int tid = threadIdx.x, lane = tid & 63, wv = tid >> 6;
  int wr = wv >> 2, wc = wv & 3;
  int nf = (blockIdx.x & 7) * 32 + (blockIdx.x >> 3);   // XCD swizzle, 256%8==0
  int M0 = (nf & 63) * 256;
  int nt = nf >> 6;
  int j0 = nt * 128;

  __hip_bfloat16* sA0 = smem;                // 256x64
  __hip_bfloat16* sA1 = smem + 16384;
  __hip_bfloat16* sB0 = smem + 32768;        // 128x64
  __hip_bfloat16* sB1 = smem + 40960;

  f32x4 accE[8][2] = {};
  f32x4 accO[8][2] = {};

#define SGA(KT, G, LB)                                                         \
  {                                                                            \
    int r_ = (G) * 64 + (tid >> 3);                                            \
    int s_ = (((tid & 7) ^ (r_ & 7)) * 8);                                     \
    gload_lds16(A + (size_t)(M0 + r_) * 1024 + (KT) * 64 + s_,                 \
                (LB) + (G) * 4096 + tid * 8);                                  \
  }
#define SGB(KT, G, LB)                                                         \
  {                                                                            \
    int r_ = (G) * 64 + (tid >> 3);                                            \
    int s_ = (((tid & 7) ^ (r_ & 7)) * 8);                                     \
    gload_lds16(B3 + (size_t)(nt * 256 + ((KT) >= 8 ? 128 : 0) + r_) * 512 +   \
                    ((KT) & 7) * 64 + s_,                                      \
                (LB) + (G) * 4096 + tid * 8);                                  \
  }
#define VMCNT(N) asm volatile("s_waitcnt vmcnt(" #N ")" ::: "memory")
#define BAR() __builtin_amdgcn_s_barrier()

#define LOADA(CA, P)                                                           \
  _Pragma("unroll") for (int jj = 0; jj < 4; ++jj) {                           \
    int row = wr * 128 + (P) * 64 + jj * 16 + (lane & 15);                     \
    _Pragma("unroll") for (int ks = 0; ks < 2; ++ks)                           \
        af[jj][ks] = *(const bf16x8*)&(CA)[row * 64 +                          \
            (((ks * 4 + (lane >> 4)) ^ (row & 7)) * 8)];                       \
  }
#define MFMAH(ACC, P)                                                          \
  __builtin_amdgcn_s_setprio(1);                                               \
  _Pragma("unroll") for (int jj = 0; jj < 4; ++jj)                             \
  _Pragma("unroll") for (int ks = 0; ks < 2; ++ks)                             \
  _Pragma("unroll") for (int ni = 0; ni < 2; ++ni)                             \
      ACC[(P) * 4 + jj][ni] = __builtin_amdgcn_mfma_f32_16x16x32_bf16(         \
          af[jj][ks], bfr[ks][ni], ACC[(P) * 4 + jj][ni], 0, 0, 0);            \
  __builtin_amdgcn_s_setprio(0);

// One K-tile, 2 phases. FIFO: tile starts with B(2)+A g0,g2 landed, A g1,g3 (2)
// in flight. ph0 issues next-B(2); mid VMCNT(2) drains old A g1,g3. ph1 issues
// next-A (g0,g2,g1,g3); end VMCNT(2) drains B+A g0,g2, leaves A g1,g3.
#define TILE(CA, CB, NA, NBUF, K1, DOST, ACC)                                  \
  {                                                                            \
    bf16x8 bfr[2][2], af[4][2];                                                \
    _Pragma("unroll") for (int ni = 0; ni < 2; ++ni) {                         \
      int row = wc * 32 + ni * 16 + (lane & 15);                               \
      _Pragma("unroll") for (int ks = 0; ks < 2; ++ks)                         \
          bfr[ks][ni] = *(const bf16x8*)&(CB)[row * 64 +                       \
              (((ks * 4 + (lane >> 4)) ^ (row & 7)) * 8)];                     \
    }                                                                          \
    LOADA(CA, 0);                                                              \
    if (DOST) { SGB(K1, 0, NBUF); SGB(K1, 1, NBUF); }                          \
    BAR(); MFMAH(ACC, 0);                                                      \
    if (DOST) { VMCNT(2); } else { VMCNT(0); }                                 \
    BAR();                                                                     \
    LOADA(CA, 1);                                                              \
    if (DOST) { SGA(K1, 0, NA); SGA(K1, 2, NA); SGA(K1, 1, NA); SGA(K1, 3, NA); } \
    BAR(); MFMAH(ACC, 1);                                                      \
    if (DOST) { VMCNT(2); }                                                    \
    BAR();                                                                     \
  }

  // prologue: tile 0 -> buf0
  SGB(0, 0, sB0); SGB(0, 1, sB0);
  SGA(0, 0, sA0); SGA(0, 2, sA0);
  SGA(0, 1, sA0); SGA(0, 3, sA0);
  VMCNT(2);   // B + A g0,g2 landed; A g1,g3 in flight
  BAR();

#pragma unroll
  for (int tt = 0; tt < 4; ++tt) {                 // tiles 0..7: E
    TILE(sA0, sB0, sA1, sB1, 2 * tt + 1, 1, accE);
    TILE(sA1, sB1, sA0, sB0, 2 * tt + 2, 1, accE);
  }
#pragma unroll
  for (int tt = 0; tt < 4; ++tt) {                 // tiles 8..15: O
    TILE(sA0, sB0, sA1, sB1, 2 * tt + 9, 1, accO);
    TILE(sA1, sB1, sA0, sB0, 2 * tt + 10, (tt < 3) ? 1 : 0, accO);
  }

  // epilogue: combine E/O with window, bounce through LDS, coalesced stores
  __hip_bfloat16* ct = smem;                 // 256 x 256 bf16
  float wE[2], wO[2];
#pragma unroll
  for (int ni = 0; ni < 2; ++ni) {
    int jcol = j0 + wc * 32 + ni * 16 + (lane & 15);
    wE[ni] = wint[jcol];
    wO[ni] = wint[jcol + 512];
  }
#pragma unroll
  for (int mi = 0; mi < 8; ++mi) {
    int rbase = wr * 128 + mi * 16 + (lane >> 4) * 4;
#pragma unroll
    for (int ni = 0; ni < 2; ++ni) {
      int lc = wc * 32 + ni * 16 + (lane & 15);
#pragma unroll
      for (int r = 0; r < 4; ++r) {
        float E = accE[mi][ni][r], O = accO[mi][ni][r];
        ct[(rbase + r) * 256 + lc] = __float2bfloat16(wE[ni] * (E + O));
        ct[(rbase + r) * 256 + 128 + lc] = __float2bfloat16(wO[ni] * (E - O));
      }
    }
  }
  BAR();
#pragma unroll
  for (int k = 0; k < 16; ++k) {
    int row = k * 16 + (tid >> 5);
    int c0 = (tid & 31) * 8;
    int gcol = (c0 < 128) ? (j0 + c0) : (512 + j0 + c0 - 128);
    *(int4*)(C + (size_t)(M0 + row) * 1024 + gcol) = *(const int4*)&ct[row * 256 + c0];
  }
#undef SGA
#undef SGB
#undef VMCNT
#undef BAR
#undef LOADA
#undef MFMAH
#undef TILE
}

// OLA: out[b][256q+r] = sum_{t=q-3..q, clamped} C[b*1024+t][(256q+r)-256t].
// Interior q: 4 contiguous aligned bf16x8 spans. Edge q: clamped scalar path.
__global__ void ola2(const __hip_bfloat16* __restrict__ C, float* __restrict__ out) {
  int q = blockIdx.x;                        // 0..1026
  int b = blockIdx.y * 8 + (threadIdx.x >> 5);
  int r0 = (threadIdx.x & 31) * 8;
  size_t outl = (size_t)b * LOUT + q * 256 + r0;
  if (q >= 3 && q < 1024) {
    size_t mrow = ((size_t)b * 1024 + q) * 1024;
    bf16x8 v0 = *(const bf16x8*)&C[mrow + r0];
    bf16x8 v1 = *(const bf16x8*)&C[mrow - 1024 + 256 + r0];
    bf16x8 v2 = *(const bf16x8*)&C[mrow - 2048 + 512 + r0];
    bf16x8 v3 = *(const bf16x8*)&C[mrow - 3072 + 768 + r0];
    float res[8];
#pragma unroll
    for (int e = 0; e < 8; ++e)
      res[e] = (float)v0[e] + (float)v1[e] + (float)v2[e] + (float)v3[e];
    *(float4*)(out + outl) = make_float4(res[0], res[1], res[2], res[3]);
    *(float4*)(out + outl + 4) = make_float4(res[4], res[5], res[6], res[7]);
    return;
  }
#pragma unroll
  for (int e = 0; e < 8; ++e) {
    int l = q * 256 + r0 + e;
    int thi = l >> 8; if (thi > 1023) thi = 1023;
    int tlo = (l - 768) >> 8; if (tlo < 0) tlo = 0;
    float s = 0.f;
    for (int t = tlo; t <= thi; ++t)
      s += __bfloat162float(C[((size_t)b * 1024 + t) * 1024 + (l - (t << 8))]);
    out[outl + e] = s;
  }
}

extern "C" void kernel_launch(void* const* d_in, const int* in_sizes, int n_in,
                              void* d_out, int out_size, void* d_ws, size_t ws_size,
                              hipStream_t stream) {
  (void)in_sizes; (void)n_in; (void)out_size; (void)ws_size;
  const float* x = (const float*)d_in[0];
  float* out = (float*)d_out;
  char* ws = (char*)d_ws;
  size_t oA  = 0;
  size_t oB3 = oA + (size_t)MM * 1024 * 2;         // 33.55 MB
  size_t oW  = oB3 + (size_t)1024 * 512 * 2;       // +1 MB
  size_t oC  = oW + 1024 * 4;
  __hip_bfloat16* A  = (__hip_bfloat16*)(ws + oA);
  __hip_bfloat16* B3 = (__hip_bfloat16*)(ws + oB3);
  float* wint = (float*)(ws + oW);
  __hip_bfloat16* C  = (__hip_bfloat16*)(ws + oC);

  prep<<<dim3(PACK_BLOCKS + 2048), dim3(256), 0, stream>>>(x, A, B3, wint);
  gemm8<<<dim3(256), dim3(512), 0, stream>>>(A, B3, wint, C);
  ola2<<<dim3(1027, 2), dim3(256), 0, stream>>>(C, out);
}

// Round 15
// 60.920 us; speedup vs baseline: 1.2345x; 1.0524x over previous
//
#include <hip/hip_runtime.h>
#include <hip/hip_bf16.h>

#define HOP 256
#define NB 16
#define NT 1024
#define MM (NB*NT)                 // 16384
#define LOUT ((NT-1)*HOP + 1024)   // 262912
#define CQ (2.0f/(3.0f*1024.0f))   // (HOP/sum(win^2))/NFFT
#define PACK_BLOCKS 2048           // 16 b x 8 f-tiles x 16 t-tiles

typedef __bf16 bf16x8 __attribute__((ext_vector_type(8)));
typedef float f32x4 __attribute__((ext_vector_type(4)));

__device__ __forceinline__ void gload_lds16(const void* g, void* l) {
  __builtin_amdgcn_global_load_lds(
      (const __attribute__((address_space(1))) void*)g,
      (__attribute__((address_space(3))) void*)l, 16, 0, 0);
}

// Radix-2 frequency split (identical to verified round-14 prep).
// A2[m][c]: c in [0,257): re f=2c | [257,512): im f=2(c-256) | [512,768): re f=2(c-512)+1
//   | [768,1024): im f=2(c-768)+1.  (im f=0 dropped: zero kernel; re f=512 at c=256.)
// B3[row][c], row in [0,1024): nt=row>>8, i=row&255; i<128: E-row j=nt*128+i,
//   i>=128: O-row j=nt*128+i-128. wint[j]=win[j]*CQ.
// frame[j]=wint[j]*(E+O), frame[j+512]=wint[j+512]*(E-O).
__global__ void prep(const float* __restrict__ x, __hip_bfloat16* __restrict__ A,
                     __hip_bfloat16* __restrict__ B3, float* __restrict__ wint) {
  int tid = threadIdx.x;
  if (blockIdx.x >= PACK_BLOCKS) {
    int idx = (blockIdx.x - PACK_BLOCKS) * 256 + tid;   // [0, 1024*512)
    int row = idx >> 9, c = idx & 511;
    int i = row & 255, nt = row >> 8;
    int oddh = i >> 7;
    int j = nt * 128 + (i & 127);
    int f, isSin;
    if (!oddh) {
      if (c < 257) { f = 2 * c; isSin = 0; } else { f = 2 * (c - 256); isSin = 1; }
    } else {
      if (c < 256) { f = 2 * c + 1; isSin = 0; } else { f = 2 * (c - 256) + 1; isSin = 1; }
    }
    const float w0 = 6.283185307179586f / 1024.f;
    int ph = (f * j) & 1023;
    float si, co;
    __sincosf((float)ph * w0, &si, &co);
    float sc = (f == 0 || f == 512) ? 1.f : 2.f;
    B3[idx] = __float2bfloat16(isSin ? -si * sc : co * sc);
    if (idx < 1024)
      wint[idx] = (0.5f - 0.5f * __cosf((float)idx * w0)) * CQ;
    return;
  }
  __shared__ float2 tile[64][65];
  int w = blockIdx.x;
  int b = w >> 7, fy = (w >> 4) & 7, tx = w & 15;
  int f0 = fy * 64, t0 = tx * 64;
  int tl = tid & 63, th = tid >> 6;
#pragma unroll
  for (int r = 0; r < 16; ++r) {
    int fl = r * 4 + th;
    tile[fl][tl] = *(const float2*)(x + (((size_t)b * 513 + f0 + fl) * 1024 + (t0 + tl)) * 2);
  }
  __syncthreads();
  int row = tid >> 2, s = tid & 3;
  float sp = 0.f;
  if (fy == 0 && s == 1)
    sp = x[(((size_t)b * 513 + 512) * 1024 + t0 + row) * 2];   // re512 -> c=256
  int cbase = (s & 1) * 256 + (s >> 1) * 512 + f0 / 2;
#pragma unroll
  for (int v = 0; v < 4; ++v) {
    bf16x8 pv;
#pragma unroll
    for (int u = 0; u < 8; ++u) {
      int e = v * 8 + u;
      float2 tv = tile[2 * e + (s >> 1)][row];
      float val = (s & 1) ? tv.y : tv.x;
      if (fy == 0 && s == 1 && e == 0) val = sp;   // replace dropped im f=0
      pv[u] = (__bf16)val;
    }
    *(bf16x8*)(A + (size_t)(b * 1024 + t0 + row) * 1024 + cbase + v * 8) = pv;
  }
}

// 128m x 128j tile, BK=64, 8 waves (2M x 4N), 64 KB LDS -> 2 blocks/CU.
// Stage-next at tile START (max issue->wait distance), 1 barrier/tile, VMCNT(0)
// drain at tile end; cross-block co-residency hides it. 3-bit slot swizzle
// (rule 21), setprio (T5). XCD co-location: the 4 nt-blocks of one M-panel are
// consecutive bids on one XCD -> A panel L2-shared. K-tiles 0..7: E, 8..15: O.
__global__ __launch_bounds__(512, 4) void gemm8(
    const __hip_bfloat16* __restrict__ A, const __hip_bfloat16* __restrict__ B3,
    const float* __restrict__ wint, __hip_bfloat16* __restrict__ C) {
  __shared__ __align__(16) __hip_bfloat16 smem[32768];  // 64 KB
  int tid = threadIdx.x, lane = tid & 63, wv = tid >> 6;
  int wr = wv >> 2, wc = wv & 3;
  int q = blockIdx.x >> 3, xcd = blockIdx.x & 7;
  int m_ = xcd + 8 * (q >> 2);     // [0,128): same m_ -> 4 consecutive bids, 1 XCD
  int nt = q & 3;
  int M0 = m_ * 128;
  int j0 = nt * 128;

  __hip_bfloat16* sA0 = smem;                // 128x64
  __hip_bfloat16* sA1 = smem + 8192;
  __hip_bfloat16* sB0 = smem + 16384;        // 128x64
  __hip_bfloat16* sB1 = smem + 24576;

  f32x4 accE[4][2] = {};
  f32x4 accO[4][2] = {};

#define SGA(KT, G, LB)                                                         \
  {                                                                            \
    int r_ = (G) * 64 + (tid >> 3);                                            \
    int s_ = (((tid & 7) ^ (r_ & 7)) * 8);                                     \
    gload_lds16(A + (size_t)(M0 + r_) * 1024 + (KT) * 64 + s_,                 \
                (LB) + (G) * 4096 + tid * 8);                                  \
  }
#define SGB(KT, G, LB)                                                         \
  {                                                                            \
    int r_ = (G) * 64 + (tid >> 3);                                            \
    int s_ = (((tid & 7) ^ (r_ & 7)) * 8);                                     \
    gload_lds16(B3 + (size_t)(nt * 256 + ((KT) >= 8 ? 128 : 0) + r_) * 512 +   \
                    ((KT) & 7) * 64 + s_,                                      \
                (LB) + (G) * 4096 + tid * 8);                                  \
  }
#define VMCNT0() asm volatile("s_waitcnt vmcnt(0)" ::: "memory")
#define BAR() __builtin_amdgcn_s_barrier()

// One K-tile: stage next tile FIRST (other buffer), then 12 ds_reads, 16 MFMA,
// drain + single barrier.
#define TILE(CA, CB, NA, NBUF, K1, DOST, ACC)                                  \
  {                                                                            \
    if (DOST) { SGB(K1, 0, NBUF); SGB(K1, 1, NBUF);                            \
                SGA(K1, 0, NA);   SGA(K1, 1, NA); }                            \
    bf16x8 bfr[2][2], af[4][2];                                                \
    _Pragma("unroll") for (int ni = 0; ni < 2; ++ni) {                         \
      int row = wc * 32 + ni * 16 + (lane & 15);                               \
      _Pragma("unroll") for (int ks = 0; ks < 2; ++ks)                         \
          bfr[ks][ni] = *(const bf16x8*)&(CB)[row * 64 +                       \
              (((ks * 4 + (lane >> 4)) ^ (row & 7)) * 8)];                     \
    }                                                                          \
    _Pragma("unroll") for (int mi = 0; mi < 4; ++mi) {                         \
      int row = wr * 64 + mi * 16 + (lane & 15);                               \
      _Pragma("unroll") for (int ks = 0; ks < 2; ++ks)                         \
          af[mi][ks] = *(const bf16x8*)&(CA)[row * 64 +                        \
              (((ks * 4 + (lane >> 4)) ^ (row & 7)) * 8)];                     \
    }                                                                          \
    __builtin_amdgcn_s_setprio(1);                                             \
    _Pragma("unroll") for (int mi = 0; mi < 4; ++mi)                           \
    _Pragma("unroll") for (int ks = 0; ks < 2; ++ks)                           \
    _Pragma("unroll") for (int ni = 0; ni < 2; ++ni)                           \
        ACC[mi][ni] = __builtin_amdgcn_mfma_f32_16x16x32_bf16(                 \
            af[mi][ks], bfr[ks][ni], ACC[mi][ni], 0, 0, 0);                    \
    __builtin_amdgcn_s_setprio(0);                                             \
    VMCNT0();                                                                  \
    BAR();                                                                     \
  }

  // prologue: tile 0 -> buf0
  SGB(0, 0, sB0); SGB(0, 1, sB0);
  SGA(0, 0, sA0); SGA(0, 1, sA0);
  VMCNT0();
  BAR();

#pragma unroll
  for (int tt = 0; tt < 4; ++tt) {                 // tiles 0..7: E
    TILE(sA0, sB0, sA1, sB1, 2 * tt + 1, 1, accE);
    TILE(sA1, sB1, sA0, sB0, 2 * tt + 2, 1, accE);
  }
#pragma unroll
  for (int tt = 0; tt < 4; ++tt) {                 // tiles 8..15: O
    TILE(sA0, sB0, sA1, sB1, 2 * tt + 9, 1, accO);
    TILE(sA1, sB1, sA0, sB0, 2 * tt + 10, (tt < 3) ? 1 : 0, accO);
  }

  // epilogue: combine E/O with window, bounce through LDS, coalesced stores
  __hip_bfloat16* ct = smem;                 // 128 x 256 bf16 (64 KB, reuse)
  float wE[2], wO[2];
#pragma unroll
  for (int ni = 0; ni < 2; ++ni) {
    int jcol = j0 + wc * 32 + ni * 16 + (lane & 15);
    wE[ni] = wint[jcol];
    wO[ni] = wint[jcol + 512];
  }
#pragma unroll
  for (int mi = 0; mi < 4; ++mi) {
    int rbase = wr * 64 + mi * 16 + (lane >> 4) * 4;
#pragma unroll
    for (int ni = 0; ni < 2; ++ni) {
      int lc = wc * 32 + ni * 16 + (lane & 15);
#pragma unroll
      for (int r = 0; r < 4; ++r) {
        float E = accE[mi][ni][r], O = accO[mi][ni][r];
        ct[(rbase + r) * 256 + lc] = __float2bfloat16(wE[ni] * (E + O));
        ct[(rbase + r) * 256 + 128 + lc] = __float2bfloat16(wO[ni] * (E - O));
      }
    }
  }
  BAR();
#pragma unroll
  for (int k = 0; k < 8; ++k) {
    int row = k * 16 + (tid >> 5);
    int c0 = (tid & 31) * 8;
    int gcol = (c0 < 128) ? (j0 + c0) : (512 + j0 + c0 - 128);
    *(int4*)(C + (size_t)(M0 + row) * 1024 + gcol) = *(const int4*)&ct[row * 256 + c0];
  }
#undef SGA
#undef SGB
#undef VMCNT0
#undef BAR
#undef TILE
}

// OLA: out[b][256q+r] = sum_{t=q-3..q, clamped} C[b*1024+t][(256q+r)-256t].
// Interior q: 4 contiguous aligned bf16x8 spans. Edge q: clamped scalar path.
__global__ void ola2(const __hip_bfloat16* __restrict__ C, float* __restrict__ out) {
  int q = blockIdx.x;                        // 0..1026
  int b = blockIdx.y * 8 + (threadIdx.x >> 5);
  int r0 = (threadIdx.x & 31) * 8;
  size_t outl = (size_t)b * LOUT + q * 256 + r0;
  if (q >= 3 && q < 1024) {
    size_t mrow = ((size_t)b * 1024 + q) * 1024;
    bf16x8 v0 = *(const bf16x8*)&C[mrow + r0];
    bf16x8 v1 = *(const bf16x8*)&C[mrow - 1024 + 256 + r0];
    bf16x8 v2 = *(const bf16x8*)&C[mrow - 2048 + 512 + r0];
    bf16x8 v3 = *(const bf16x8*)&C[mrow - 3072 + 768 + r0];
    float res[8];
#pragma unroll
    for (int e = 0; e < 8; ++e)
      res[e] = (float)v0[e] + (float)v1[e] + (float)v2[e] + (float)v3[e];
    *(float4*)(out + outl) = make_float4(res[0], res[1], res[2], res[3]);
    *(float4*)(out + outl + 4) = make_float4(res[4], res[5], res[6], res[7]);
    return;
  }
#pragma unroll
  for (int e = 0; e < 8; ++e) {
    int l = q * 256 + r0 + e;
    int thi = l >> 8; if (thi > 1023) thi = 1023;
    int tlo = (l - 768) >> 8; if (tlo < 0) tlo = 0;
    float s = 0.f;
    for (int t = tlo; t <= thi; ++t)
      s += __bfloat162float(C[((size_t)b * 1024 + t) * 1024 + (l - (t << 8))]);
    out[outl + e] = s;
  }
}

extern "C" void kernel_launch(void* const* d_in, const int* in_sizes, int n_in,
                              void* d_out, int out_size, void* d_ws, size_t ws_size,
                              hipStream_t stream) {
  (void)in_sizes; (void)n_in; (void)out_size; (void)ws_size;
  const float* x = (const float*)d_in[0];
  float* out = (float*)d_out;
  char* ws = (char*)d_ws;
  size_t oA  = 0;
  size_t oB3 = oA + (size_t)MM * 1024 * 2;         // 33.55 MB
  size_t oW  = oB3 + (size_t)1024 * 512 * 2;       // +1 MB
  size_t oC  = oW + 1024 * 4;
  __hip_bfloat16* A  = (__hip_bfloat16*)(ws + oA);
  __hip_bfloat16* B3 = (__hip_bfloat16*)(ws + oB3);
  float* wint = (float*)(ws + oW);
  __hip_bfloat16* C  = (__hip_bfloat16*)(ws + oC);

  prep<<<dim3(PACK_BLOCKS + 2048), dim3(256), 0, stream>>>(x, A, B3, wint);
  gemm8<<<dim3(512), dim3(512), 0, stream>>>(A, B3, wint, C);
  ola2<<<dim3(1027, 2), dim3(256), 0, stream>>>(C, out);
}